// Round 7
// baseline (764.061 us; speedup 1.0000x reference)
//
#include <hip/hip_runtime.h>

typedef unsigned short u16;
typedef unsigned int u32;
typedef unsigned long long u64;
typedef int   v4i  __attribute__((ext_vector_type(4)));
typedef short v8s  __attribute__((ext_vector_type(8)));
typedef float v2f  __attribute__((ext_vector_type(2)));
typedef float v4f  __attribute__((ext_vector_type(4)));

#define B_ 256
#define T_ 120
#define E_ 256
#define H_ 1024
#define LDH 1032    // 1024 + 8 pad (u16); stride 2064B, 16B-aligned, halves contiguous
#define LDX 264     // 256 + 8 pad

// ---- ws layout (bytes) ----
#define WS_WF   0                    // 10,485,760  (W fragments, bf16)
#define WS_X    10485760             // 15,728,640  (X (T,B,E) bf16)
#define WS_HS   26214400             // 62,914,560  (hs (T,B,H) bf16)
#define WS_BAR  89128960             // 122,880 (16 chains x 120 steps, 64B-padded)

__device__ __forceinline__ u16 f2bf(float f) {
    union { float f; u32 u; } v; v.f = f;
    u32 r = v.u + 0x7fffu + ((v.u >> 16) & 1u);   // RNE
    return (u16)(r >> 16);
}
__device__ __forceinline__ float bf2f(u16 u) {
    union { u32 u; float f; } v; v.u = ((u32)u) << 16; return v.f;
}
__device__ __forceinline__ float fsig(float x) {
    float t = __builtin_amdgcn_exp2f(-1.44269504f * x);
    return __builtin_amdgcn_rcpf(1.0f + t);
}
__device__ __forceinline__ float ftanh_(float x) {
    float xc = fminf(8.0f, fmaxf(-8.0f, x));
    float t = __builtin_amdgcn_exp2f(2.88539008f * xc);
    return (t - 1.0f) * __builtin_amdgcn_rcpf(t + 1.0f);
}
__device__ __forceinline__ void gl_lds16(const void* g, void* l) {
    __builtin_amdgcn_global_load_lds(
        (const __attribute__((address_space(1))) void*)g,
        (__attribute__((address_space(3))) void*)l, 16, 0, 0);
}

// ---------------- P1 (merged): W transform + embedding gather ----------------
// 16x16x32 B-fragments. cid = nc*8 + g*2 + kh (0..255). Wave (g,kh) owns gate g,
// cols nc*32..+32 (2 n-tiles of 16), K-frags s = 2f+kh (f 0..19; f<4 = x-part).
// Frag elem (l,j) = W[32*(2f+kh) + (l>>4)*8 + j][g*1024 + nc*32 + n*16 + (l&15)].
__global__ void prep_all(const float* __restrict__ W, u16* __restrict__ Wf,
                         const int* __restrict__ tokens, const float* __restrict__ emb,
                         u16* __restrict__ X) {
    __shared__ u16 tile[32 * 136];        // [col(32)][fl*32+krow, +8 pad]
    int bid = blockIdx.x;
    int tid = threadIdx.x;
    if (bid < 1280) {
        int cid = bid / 5, fo = bid % 5;
        int kh = cid & 1, g = (cid >> 1) & 3, nc = cid >> 3;
        int colbase = g * 1024 + nc * 32;
        int cc = tid & 31, rr = tid >> 5;  // rr 0..7
#pragma unroll
        for (int fl = 0; fl < 4; ++fl) {
            int k0 = 32 * (2 * (fo * 4 + fl) + kh);
#pragma unroll
            for (int q = 0; q < 4; ++q) {
                int krow = rr + q * 8;     // 0..31
                float v = W[(size_t)(k0 + krow) * 4096 + colbase + cc];
                tile[cc * 136 + fl * 32 + krow] = f2bf(v);
            }
        }
        __syncthreads();
        int lane = tid & 63, wvv = tid >> 6;
#pragma unroll
        for (int pass = 0; pass < 2; ++pass) {
            int u = wvv + pass * 4;        // unit: fl = u>>1, n = u&1
            int fl = u >> 1, n = u & 1;
            v4i o = *(const v4i*)&tile[(n * 16 + (lane & 15)) * 136 + fl * 32 + ((lane >> 4) << 3)];
            *(v4i*)(Wf + (size_t)cid * 20480 + ((size_t)((fo * 4 + fl) * 2 + n) << 9) + lane * 8) = o;
        }
    } else {
        int v   = (bid - 1280) * 256 + tid;           // < 983040
        int e8  = v & 31;
        int row = v >> 5;                             // t*256 + b
        int t = row >> 8, b = row & 255;
        int tok = tokens[b * T_ + t];
        const float* src = emb + (size_t)tok * E_ + e8 * 8;
        u16 o[8];
#pragma unroll
        for (int j = 0; j < 8; ++j) o[j] = f2bf(src[j]);
        *(v4i*)(X + (size_t)row * E_ + e8 * 8) = *(v4i*)o;
    }
}

// ---------------- main persistent LSTM kernel ----------------
// 256 blocks x 512 threads. Block (mchunk=bid&7, nc=bid>>3) covers 32 rows as TWO
// independent 16-row chains (A = rows m0..+16, B = m0+16..+32), phase-shifted:
// each chain's store-drain + flag RTT + h-load latency is covered by the OTHER
// chain's full GEMM+cell phase. The mandatory vmcnt(0) before each flag publish
// doubles as the drain for the other chain's global_load_lds (issued a phase ago).
// Wave (g=wv>>1, kh=wv&1): gate g, 2 n-tiles, K-parity half. W pinned: 160 VGPR.
__global__ __launch_bounds__(512, 2) void lstm_main(
    const u16* __restrict__ Wf, const u16* __restrict__ X,
    const float* __restrict__ b_lstm, u16* __restrict__ hs,
    u32* __restrict__ bar) {

    __shared__ u16  hbuf[2][16 * LDH];        // 2 x 33,024 B
    __shared__ u16  xbuf[32 * LDX];           // 16,896 B
    __shared__ float gates[8 * 544];          // 17,408 B  [kh*4+g][row16][34]
    __shared__ float bias[128];               // ~100.9 KB total

    const int tid   = threadIdx.x;
    const int lane  = tid & 63;
    const int wv    = tid >> 6;
    const int g     = wv >> 1;
    const int kh    = wv & 1;
    const int bid   = blockIdx.x;
    const int mchunk = bid & 7;
    const int nc    = bid >> 3;
    const int m0    = mchunk << 5;

    if (tid < 128) bias[tid] = b_lstm[(tid >> 5) * H_ + (nc << 5) + (tid & 31)];

    // ---- resident W fragments: [f 0..19][n 0..1], pinned (160 VGPR) ----
    v8s Wr[20][2];
    {
        const v4i* wsrc = (const v4i*)(Wf + (size_t)(nc * 8 + g * 2 + kh) * 20480);
#pragma unroll
        for (int f = 0; f < 20; ++f)
#pragma unroll
            for (int n = 0; n < 2; ++n)
                Wr[f][n] = __builtin_bit_cast(v8s, wsrc[(f * 2 + n) * 64 + lane]);
    }
#pragma unroll
    for (int f = 0; f < 20; ++f) {
        asm volatile("" : "+v"(Wr[f][0]));
        asm volatile("" : "+v"(Wr[f][1]));
    }

    // ---- stage X_0 (rows m0..m0+32) ----
    {
        const v4i* xs = (const v4i*)(X + (size_t)m0 * E_);
#pragma unroll
        for (int i = 0; i < 2; ++i) {
            int idx = tid + i * 512;
            int r = idx >> 5, c8 = idx & 31;
            *(v4i*)&xbuf[r * LDX + c8 * 8] = xs[r * 32 + c8];
        }
    }
    __syncthreads();

    const int arow = lane & 15, aq = (lane >> 4) << 3;
    const u16* Ax0 = &xbuf[arow * LDX + aq];
    const u16* Ax1 = &xbuf[(16 + arow) * LDX + aq];
    const u16* Ah0 = &hbuf[0][arow * LDH + aq];
    const u16* Ah1 = &hbuf[1][arow * LDH + aq];

    float cstA[2] = {0.f, 0.f}, cstB[2] = {0.f, 0.f};
    const int cm  = tid >> 4;                 // 0..15 for tid<256
    const int cn2 = (tid & 15) << 1;
    const int gcol = lane & 15, gr4 = (lane >> 4) << 2;
    u32* hs32 = (u32*)hs;

    for (int t = 0; t < T_; ++t) {
        // ===== [1/2] poll chain-B flag(t-1), issue B h-loads (fly through A phase) =====
        if (t > 0) {
            if (tid == 0) {
                u32* p = &bar[((size_t)((mchunk * 2 + 1) * T_ + (t - 1))) << 4];
                while (__hip_atomic_load(p, __ATOMIC_RELAXED, __HIP_MEMORY_SCOPE_AGENT) < 32u)
                    __builtin_amdgcn_s_sleep(1);
            }
            __syncthreads();
            const u16* src = hs + ((size_t)(t - 1) * B_ + m0 + 16) * H_;
#pragma unroll
            for (int i = 0; i < 4; ++i) {
                int idx = wv * 4 + i, r = idx >> 1, hf = idx & 1;
                gl_lds16(src + (size_t)r * H_ + hf * 512 + lane * 8,
                         &hbuf[1][r * LDH + hf * 512]);
            }
        }

        // ===== [3] chain-A phase, step t (hbuf[0] drained by prev iter's vmcnt(0)) =====
        v4f a0 = {0,0,0,0}, a1 = {0,0,0,0};
#pragma unroll
        for (int f = 0; f < 4; ++f) {
            v8s a = *(const v8s*)(Ax0 + (2 * f + kh) * 32);
            a0 = __builtin_amdgcn_mfma_f32_16x16x32_bf16(a, Wr[f][0], a0, 0, 0, 0);
            a1 = __builtin_amdgcn_mfma_f32_16x16x32_bf16(a, Wr[f][1], a1, 0, 0, 0);
        }
        if (t > 0) {
#pragma unroll
            for (int f = 4; f < 20; ++f) {
                v8s a = *(const v8s*)(Ah0 + (64 * f + 32 * kh - 256));
                a0 = __builtin_amdgcn_mfma_f32_16x16x32_bf16(a, Wr[f][0], a0, 0, 0, 0);
                a1 = __builtin_amdgcn_mfma_f32_16x16x32_bf16(a, Wr[f][1], a1, 0, 0, 0);
            }
        }
        {   // C/D 16x16: col=lane&15, row=(lane>>4)*4+reg
            float* gb = &gates[(kh * 4 + g) * 544];
#pragma unroll
            for (int reg = 0; reg < 4; ++reg) {
                int row = gr4 + reg;
                gb[row * 34 + gcol]      = a0[reg];
                gb[row * 34 + 16 + gcol] = a1[reg];
            }
        }
        __syncthreads();
        if (tid < 256) {                      // cell A: 16 rows x 32 cols
            v2f zz[4];
#pragma unroll
            for (int gg = 0; gg < 4; ++gg) {
                v2f s0 = *(const v2f*)&gates[(0 + gg) * 544 + cm * 34 + cn2];
                v2f s1 = *(const v2f*)&gates[(4 + gg) * 544 + cm * 34 + cn2];
                zz[gg].x = s0.x + s1.x; zz[gg].y = s0.y + s1.y;
            }
            u32 hpack = 0;
#pragma unroll
            for (int q = 0; q < 2; ++q) {
                int n = cn2 + q;
                float ip = zz[0][q] + bias[n];
                float jp = zz[1][q] + bias[32 + n];
                float fp = zz[2][q] + bias[64 + n] + 1.0f;
                float op = zz[3][q] + bias[96 + n];
                float cc = fsig(fp) * cstA[q] + fsig(ip) * ftanh_(jp);
                cstA[q] = cc;
                hpack |= ((u32)f2bf(fsig(op) * ftanh_(cc))) << (16 * q);
            }
            __hip_atomic_store(&hs32[((size_t)t * B_ + m0 + cm) * 512 + (nc << 4) + (tid & 15)],
                               hpack, __ATOMIC_RELAXED, __HIP_MEMORY_SCOPE_AGENT);
        }
        // drain A-store (also completes B h-loads issued at [2]); publish flag A(t)
        asm volatile("s_waitcnt vmcnt(0)" ::: "memory");
        __syncthreads();
        // ===== [5] publish+poll A(t), issue A h-loads for t+1 (fly through B phase) =====
        if (t + 1 < T_) {
            if (tid == 0) {
                u32* p = &bar[((size_t)((mchunk * 2 + 0) * T_ + t)) << 4];
                __hip_atomic_fetch_add(p, 1u, __ATOMIC_RELAXED, __HIP_MEMORY_SCOPE_AGENT);
                while (__hip_atomic_load(p, __ATOMIC_RELAXED, __HIP_MEMORY_SCOPE_AGENT) < 32u)
                    __builtin_amdgcn_s_sleep(1);
            }
            __syncthreads();
            const u16* src = hs + ((size_t)t * B_ + m0) * H_;
#pragma unroll
            for (int i = 0; i < 4; ++i) {
                int idx = wv * 4 + i, r = idx >> 1, hf = idx & 1;
                gl_lds16(src + (size_t)r * H_ + hf * 512 + lane * 8,
                         &hbuf[0][r * LDH + hf * 512]);
            }
        }

        // ===== [6] chain-B phase, step t (hbuf[1] drained at A's vmcnt(0)) =====
        v4f b0 = {0,0,0,0}, b1 = {0,0,0,0};
#pragma unroll
        for (int f = 0; f < 4; ++f) {
            v8s a = *(const v8s*)(Ax1 + (2 * f + kh) * 32);
            b0 = __builtin_amdgcn_mfma_f32_16x16x32_bf16(a, Wr[f][0], b0, 0, 0, 0);
            b1 = __builtin_amdgcn_mfma_f32_16x16x32_bf16(a, Wr[f][1], b1, 0, 0, 0);
        }
        if (t > 0) {
#pragma unroll
            for (int f = 4; f < 20; ++f) {
                v8s a = *(const v8s*)(Ah1 + (64 * f + 32 * kh - 256));
                b0 = __builtin_amdgcn_mfma_f32_16x16x32_bf16(a, Wr[f][0], b0, 0, 0, 0);
                b1 = __builtin_amdgcn_mfma_f32_16x16x32_bf16(a, Wr[f][1], b1, 0, 0, 0);
            }
        }
        {
            float* gb = &gates[(kh * 4 + g) * 544];
#pragma unroll
            for (int reg = 0; reg < 4; ++reg) {
                int row = gr4 + reg;
                gb[row * 34 + gcol]      = b0[reg];
                gb[row * 34 + 16 + gcol] = b1[reg];
            }
        }
        __syncthreads();
        // x-prefetch t+1 (xbuf reads for step t all done; overlaps cell B)
        if (t + 1 < T_) {
            const v4i* xs = (const v4i*)(X + ((size_t)(t + 1) * B_ + m0) * E_);
#pragma unroll
            for (int i = 0; i < 2; ++i) {
                int idx = tid + i * 512;
                int r = idx >> 5, c8 = idx & 31;
                *(v4i*)&xbuf[r * LDX + c8 * 8] = xs[r * 32 + c8];
            }
        }
        if (tid < 256) {                      // cell B
            v2f zz[4];
#pragma unroll
            for (int gg = 0; gg < 4; ++gg) {
                v2f s0 = *(const v2f*)&gates[(0 + gg) * 544 + cm * 34 + cn2];
                v2f s1 = *(const v2f*)&gates[(4 + gg) * 544 + cm * 34 + cn2];
                zz[gg].x = s0.x + s1.x; zz[gg].y = s0.y + s1.y;
            }
            u32 hpack = 0;
#pragma unroll
            for (int q = 0; q < 2; ++q) {
                int n = cn2 + q;
                float ip = zz[0][q] + bias[n];
                float jp = zz[1][q] + bias[32 + n];
                float fp = zz[2][q] + bias[64 + n] + 1.0f;
                float op = zz[3][q] + bias[96 + n];
                float cc = fsig(fp) * cstB[q] + fsig(ip) * ftanh_(jp);
                cstB[q] = cc;
                hpack |= ((u32)f2bf(fsig(op) * ftanh_(cc))) << (16 * q);
            }
            __hip_atomic_store(&hs32[((size_t)t * B_ + m0 + 16 + cm) * 512 + (nc << 4) + (tid & 15)],
                               hpack, __ATOMIC_RELAXED, __HIP_MEMORY_SCOPE_AGENT);
        }
        // drain B-store + x-prefetch (+ A h-loads from [5]); publish flag B(t)
        asm volatile("s_waitcnt vmcnt(0)" ::: "memory");
        __syncthreads();
        if (t + 1 < T_ && tid == 0)
            __hip_atomic_fetch_add(&bar[((size_t)((mchunk * 2 + 1) * T_ + t)) << 4], 1u,
                                   __ATOMIC_RELAXED, __HIP_MEMORY_SCOPE_AGENT);
    }
}

// ---------------- P3: preds = hs @ U + b2 (64 rows/block; U staged once) ----------------
__global__ void proj_kernel(const u16* __restrict__ hs, const float* __restrict__ U,
                            const float* __restrict__ b2, float* __restrict__ out) {
    __shared__ float Ul[H_ * 5];
    int tid = threadIdx.x;
    for (int i = tid; i < H_ * 5; i += 256) Ul[i] = U[i];
    __syncthreads();
    int wv = tid >> 6, lane = tid & 63;
#pragma unroll 1
    for (int i = 0; i < 16; ++i) {
        int row = blockIdx.x * 64 + wv * 16 + i;   // t*256 + b, < 30720
        int t = row >> 8, b = row & 255;
        const v4i* hp = (const v4i*)(hs + (size_t)row * H_);
        float p[5] = {0.f, 0.f, 0.f, 0.f, 0.f};
#pragma unroll
        for (int half = 0; half < 2; ++half) {
            v4i hv = hp[lane * 2 + half];
            u16 us[8];
            *(v4i*)us = hv;
#pragma unroll
            for (int j = 0; j < 8; ++j) {
                float hf = bf2f(us[j]);
                int k = lane * 16 + half * 8 + j;
#pragma unroll
                for (int c = 0; c < 5; ++c) p[c] += hf * Ul[k * 5 + c];
            }
        }
#pragma unroll
        for (int c = 0; c < 5; ++c)
            for (int off = 32; off > 0; off >>= 1)
                p[c] += __shfl_down(p[c], off, 64);
        if (lane == 0) {
#pragma unroll
            for (int c = 0; c < 5; ++c)
                out[((size_t)b * T_ + t) * 5 + c] = p[c] + b2[c];
        }
    }
}

extern "C" void kernel_launch(void* const* d_in, const int* in_sizes, int n_in,
                              void* d_out, int out_size, void* d_ws, size_t ws_size,
                              hipStream_t stream) {
    const int*   tokens = (const int*)d_in[0];
    const float* emb    = (const float*)d_in[1];
    const float* W      = (const float*)d_in[2];
    const float* b_l    = (const float*)d_in[3];
    const float* U      = (const float*)d_in[4];
    const float* b2     = (const float*)d_in[5];
    float* out = (float*)d_out;

    char* ws = (char*)d_ws;
    u16* Wf  = (u16*)(ws + WS_WF);
    u16* X   = (u16*)(ws + WS_X);
    u16* hs  = (u16*)(ws + WS_HS);
    u32* bar = (u32*)(ws + WS_BAR);

    hipMemsetAsync(bar, 0, 16 * T_ * 16 * sizeof(u32), stream);
    prep_all<<<5120, 256, 0, stream>>>(W, Wf, tokens, emb, X);
    lstm_main<<<256, 512, 0, stream>>>(Wf, X, b_l, hs, bar);
    proj_kernel<<<480, 256, 0, stream>>>(hs, U, b2, out);
}